// Round 5
// baseline (180.179 us; speedup 1.0000x reference)
//
#include <hip/hip_runtime.h>
#include <hip/hip_bf16.h>
#include <math.h>

typedef __attribute__((ext_vector_type(8))) __bf16 bf16x8;
typedef __attribute__((ext_vector_type(4))) float f32x4;

__device__ __forceinline__ float sigmoid_f(float v) {
  return __builtin_amdgcn_rcpf(1.f + __expf(-v));
}
__device__ __forceinline__ float tanh_f(float z) {
  float az = fabsf(z);
  float e = __expf(-2.f * az);
  float t = (1.f - e) * __builtin_amdgcn_rcpf(1.f + e);
  return copysignf(t, z);
}
__device__ __forceinline__ bf16x8 cvt8(float4 a, float4 b) {
  bf16x8 r;
  r[0] = (__bf16)a.x; r[1] = (__bf16)a.y; r[2] = (__bf16)a.z; r[3] = (__bf16)a.w;
  r[4] = (__bf16)b.x; r[5] = (__bf16)b.y; r[6] = (__bf16)b.z; r[7] = (__bf16)b.w;
  return r;
}

// Zero LDS, zero barriers. Block = 512 threads = 8 waves covering the full 128
// output cols (wave w owns cols [16w,16w+16), weights persistent in 96 VGPRs).
// Each wave loads the full 16-row A tile (x and h) itself from global fp32 —
// the 8x intra-block re-read is L1/L2-served, HBM traffic stays compulsory.
// Depth-1 register prefetch (16 float4 in flight) hides HBM latency; waves are
// fully independent so latency also hides across the 8 resident waves/CU.
__global__ __launch_bounds__(512, 2) void augru_kernel(
    const float* __restrict__ x, const float* __restrict__ hp,
    const float* __restrict__ att,
    const float* __restrict__ Wx, const float* __restrict__ bx,
    const float* __restrict__ Wh, const float* __restrict__ bh,
    float* __restrict__ out) {
  const int tid  = threadIdx.x;
  const int wave = tid >> 6;
  const int lane = tid & 63;
  const int quad = lane >> 4;
  const int l15  = lane & 15;
  const int col  = wave * 16 + l15;  // this lane's output column

  // ---- persistent B-fragments: m = gate*2 + (0:Wx,1:Wh), gates u=0,r=1,h=2.
  // B-frag for 16x16x32: lane(l15,quad) holds W[n=col][k=kt*32+quad*8 ..+8].
  bf16x8 wf[6][4];
#pragma unroll
  for (int m = 0; m < 6; ++m) {
    const float* src = (m & 1) ? Wh : Wx;
    const float* wr  = src + ((m >> 1) * 128 + col) * 128 + quad * 8;
#pragma unroll
    for (int kt = 0; kt < 4; ++kt)
      wf[m][kt] = cvt8(*(const float4*)(wr + kt * 32), *(const float4*)(wr + kt * 32 + 4));
  }
  const float bu_  = bx[col] + bh[col];
  const float br_  = bx[128 + col] + bh[128 + col];
  const float bxh_ = bx[256 + col];
  const float bhh_ = bh[256 + col];

  const int  T     = 8;
  const int  tile0 = blockIdx.x * T;  // 512 blocks x 8 tiles x 16 rows = 65536
  const long aoff  = (long)l15 * 128 + quad * 8;  // A-fragment lane offset

  // ---- depth-1 prefetch buffers: tile's A data for x and h (16 float4/lane)
  float4 xa[8], ha[8];
  {
    const float* xr = x  + (long)tile0 * 16 * 128 + aoff;
    const float* hr = hp + (long)tile0 * 16 * 128 + aoff;
#pragma unroll
    for (int kt = 0; kt < 4; ++kt) {
      xa[2 * kt]     = *(const float4*)(xr + kt * 32);
      xa[2 * kt + 1] = *(const float4*)(xr + kt * 32 + 4);
    }
#pragma unroll
    for (int kt = 0; kt < 4; ++kt) {
      ha[2 * kt]     = *(const float4*)(hr + kt * 32);
      ha[2 * kt + 1] = *(const float4*)(hr + kt * 32 + 4);
    }
  }

  for (int t = 0; t < T; ++t) {
    const int rb = (tile0 + t) * 16;

    // convert current tile (vmcnt wait lands here, on loads issued one tile ago)
    bf16x8 xf[4], hf[4];
#pragma unroll
    for (int kt = 0; kt < 4; ++kt) {
      xf[kt] = cvt8(xa[2 * kt], xa[2 * kt + 1]);
      hf[kt] = cvt8(ha[2 * kt], ha[2 * kt + 1]);
    }

    // epilogue operands — ISSUE BEFORE the prefetch batch so waiting on them
    // later does not drain the prefetch loads (vmcnt is in-order per wave).
    // Both are L1-hot (the h tile is being read as fragments by this block).
    float4 attv = *(const float4*)(att + rb + quad * 4);
    float h0[4];
#pragma unroll
    for (int rr = 0; rr < 4; ++rr)
      h0[rr] = hp[(long)(rb + quad * 4 + rr) * 128 + col];

    // prefetch next tile — stays in flight under the MFMA + epilogue below
    if (t + 1 < T) {
      const float* xr = x  + (long)(rb + 16) * 128 + aoff;
      const float* hr = hp + (long)(rb + 16) * 128 + aoff;
#pragma unroll
      for (int kt = 0; kt < 4; ++kt) {
        xa[2 * kt]     = *(const float4*)(xr + kt * 32);
        xa[2 * kt + 1] = *(const float4*)(xr + kt * 32 + 4);
      }
#pragma unroll
      for (int kt = 0; kt < 4; ++kt) {
        ha[2 * kt]     = *(const float4*)(hr + kt * 32);
        ha[2 * kt + 1] = *(const float4*)(hr + kt * 32 + 4);
      }
    }

    f32x4 aU = (f32x4)0.f, aR = (f32x4)0.f, aHX = (f32x4)0.f, aHH = (f32x4)0.f;
#pragma unroll
    for (int kt = 0; kt < 4; ++kt) {
      aU  = __builtin_amdgcn_mfma_f32_16x16x32_bf16(xf[kt], wf[0][kt], aU, 0, 0, 0);
      aU  = __builtin_amdgcn_mfma_f32_16x16x32_bf16(hf[kt], wf[1][kt], aU, 0, 0, 0);
      aR  = __builtin_amdgcn_mfma_f32_16x16x32_bf16(xf[kt], wf[2][kt], aR, 0, 0, 0);
      aR  = __builtin_amdgcn_mfma_f32_16x16x32_bf16(hf[kt], wf[3][kt], aR, 0, 0, 0);
      aHX = __builtin_amdgcn_mfma_f32_16x16x32_bf16(xf[kt], wf[4][kt], aHX, 0, 0, 0);
      aHH = __builtin_amdgcn_mfma_f32_16x16x32_bf16(hf[kt], wf[5][kt], aHH, 0, 0, 0);
    }

    // ---- fused epilogue. C layout: col = l15-part, row = quad*4 + rr.
    const float* ap = (const float*)&attv;
#pragma unroll
    for (int rr = 0; rr < 4; ++rr) {
      const int row = rb + quad * 4 + rr;
      float u  = sigmoid_f(aU[rr] + bu_);
      float r  = sigmoid_f(aR[rr] + br_);
      float ht = tanh_f(aHX[rr] + bxh_ + r * (aHH[rr] + bhh_));
      float ua = ap[rr] * u;
      out[(long)row * 128 + col] = fmaf(ua, ht - h0[rr], h0[rr]);
    }
  }
}

extern "C" void kernel_launch(void* const* d_in, const int* in_sizes, int n_in,
                              void* d_out, int out_size, void* d_ws, size_t ws_size,
                              hipStream_t stream) {
  const float* x   = (const float*)d_in[0];
  const float* hpv = (const float*)d_in[1];
  const float* att = (const float*)d_in[2];
  const float* Wx  = (const float*)d_in[3];
  const float* bx  = (const float*)d_in[4];
  const float* Wh  = (const float*)d_in[5];
  const float* bh  = (const float*)d_in[6];
  float* out = (float*)d_out;

  augru_kernel<<<512, 512, 0, stream>>>(x, hpv, att, Wx, bx, Wh, bh, out);
}